// Round 6
// baseline (929.235 us; speedup 1.0000x reference)
//
#include <hip/hip_runtime.h>
#include <hip/hip_cooperative_groups.h>
#include <hip/hip_bf16.h>
#include <cstdint>
#include <cstddef>

namespace cg = cooperative_groups;

// B=64, N=256 leaves, E=D=U=512.
// Outputs: h_new[64*512], c_new[64*512], leaf_h_new[64*256*512] concat flat fp32.

__device__ __forceinline__ float sigmoidf_(float x) { return 1.0f / (1.0f + __expf(-x)); }

typedef __attribute__((ext_vector_type(8))) short bf16x8;
typedef __attribute__((ext_vector_type(4))) float f32x4;

__device__ __forceinline__ void load_lds16(const void* g, void* l) {
  __builtin_amdgcn_global_load_lds((const __attribute__((address_space(1))) void*)g,
                                   (__attribute__((address_space(3))) void*)l, 16, 0, 0);
}

// ---------- merged prep: cvt_inputs + weight transposes + ctrl + upd zero ----------
// Flat block partition: [0,NC) cvt; [NC,NC+1024) transpose tiles;
// [NC+1024, NC+1216) ctrl units (128 ch + 64 ctrlT); last 16 zero upd.
template<bool DO_CVT>
__global__ __launch_bounds__(256)
void prep_all(const float* __restrict__ inputs, const float* __restrict__ W_t,
              const float* __restrict__ W_j, const float* __restrict__ W_h,
              const float* __restrict__ W_T, const float* __restrict__ h0,
              __hip_bfloat16* __restrict__ inputs_bf, __hip_bfloat16* __restrict__ Wt_t,
              __hip_bfloat16* __restrict__ Wt_j, __hip_bfloat16* __restrict__ Wt_h,
              float* __restrict__ ch, float* __restrict__ ctrlT, float* __restrict__ upd) {
  const int NC = DO_CVT ? 4096 : 0;
  const int bid = blockIdx.x, tid = threadIdx.x;
  __shared__ float shf[1056];
  if (DO_CVT && bid < NC) {
    const size_t i = ((size_t)bid * 256 + tid) * 8;
    float4 v0 = *(const float4*)(inputs + i);
    float4 v1 = *(const float4*)(inputs + i + 4);
    union { __hip_bfloat16 h[8]; bf16x8 v; } u;
    u.h[0] = __float2bfloat16(v0.x); u.h[1] = __float2bfloat16(v0.y);
    u.h[2] = __float2bfloat16(v0.z); u.h[3] = __float2bfloat16(v0.w);
    u.h[4] = __float2bfloat16(v1.x); u.h[5] = __float2bfloat16(v1.y);
    u.h[6] = __float2bfloat16(v1.z); u.h[7] = __float2bfloat16(v1.w);
    *(bf16x8*)(inputs_bf + i) = u.v;
  } else if (bid < NC + 1024) {
    const int t = bid - NC;
    int z, bx, by;
    if (t < 512)      { z = 1; bx = t & 31;         by = t >> 5; }
    else if (t < 768) { z = 0; bx = (t - 512) & 15; by = (t - 512) >> 4; }
    else              { z = 2; bx = (t - 768) & 15; by = (t - 768) >> 4; }
    const int K = (z == 1) ? 1024 : 512;
    const float* W = (z == 0) ? W_t : ((z == 1) ? W_j : W_h);
    __hip_bfloat16* Wt = (z == 0) ? Wt_t : ((z == 1) ? Wt_j : Wt_h);
    float (*sh)[33] = (float(*)[33])shf;
    const int tx = tid & 31, ty = tid >> 5;
    const int k0 = bx * 32, n0 = by * 32;
#pragma unroll
    for (int i = 0; i < 4; ++i)
      sh[ty + i * 8][tx] = W[(size_t)(k0 + ty + i * 8) * 512 + n0 + tx];
    __syncthreads();
#pragma unroll
    for (int i = 0; i < 4; ++i)
      Wt[(size_t)(n0 + ty + i * 8) * K + k0 + tx] = __float2bfloat16(sh[tx][ty + i * 8]);
  } else if (bid < NC + 1024 + 192) {
    const int u = bid - NC - 1024;
    if (u < 128) {
      const int b = u >> 1;
      float* hsh = shf;
      hsh[tid]       = h0[b * 512 + tid];
      hsh[tid + 256] = h0[b * 512 + 256 + tid];
      __syncthreads();
      const int col = (u & 1) * 256 + tid;
      const float* Wp = W_h + (size_t)512 * 512 + col;
      float s = 0.f;
#pragma unroll 8
      for (int k = 0; k < 512; ++k) s += hsh[k] * Wp[(size_t)k * 512];
      ch[(size_t)b * 512 + col] = s;
    } else {
      const int b = u - 128;
      float* part = shf;
      float p = 0.f;
      for (int i = tid; i < 512; i += 256) p += h0[b * 512 + i] * W_T[512 + i];
      part[tid] = p; __syncthreads();
      for (int s = 128; s > 0; s >>= 1) { if (tid < s) part[tid] += part[tid + s]; __syncthreads(); }
      if (tid == 0) ctrlT[b] = part[0];
    }
  } else {
    const int u = bid - NC - 1024 - 192;   // 0..15
    *(float4*)(upd + ((size_t)u * 256 + tid) * 4) = float4{0.f, 0.f, 0.f, 0.f};
  }
}

// ---------- bf16 MFMA GEMM (MODE 0 only launched): C = relu(A @ Bt^T) ----------
// Grid (M/128, 4). bf16 path: dbuf LDS + prefetch; AFP32: fused-cvt staging.
// If upd_raw != nullptr also accumulate per-row dot with W_T via shfl+atomicAdd.
template<int MODE, bool AFP32>
__global__ __launch_bounds__(256)
void mfma_gemm(const __hip_bfloat16* __restrict__ A, const float* __restrict__ Af,
               const __hip_bfloat16* __restrict__ Bt, int M, int K,
               __hip_bfloat16* __restrict__ Cb, float* __restrict__ Cf,
               const float* __restrict__ ctrl_h, const float* __restrict__ attn,
               const float* __restrict__ upd_raw, const __hip_bfloat16* __restrict__ leaf,
               const float* __restrict__ W_T, const float* __restrict__ ctrlT) {
  __shared__ __align__(16) __hip_bfloat16 Asm[2][128 * 32];
  __shared__ __align__(16) __hip_bfloat16 Bsm[2][128 * 32];
  const int tid = threadIdx.x;
  const int wave = tid >> 6, lane = tid & 63;
  const int bm = blockIdx.x * 128, bn = blockIdx.y * 128;
  const int wm = (wave >> 1) * 64, wn = (wave & 1) * 64;
  const int q = lane >> 4, lr = lane & 15;

  f32x4 acc[4][4] = {};

  const int c0 = wave * 128 + lane, c1 = c0 + 64;
  const size_t ga0 = (size_t)(bm + (c0 >> 2)) * K + (c0 & 3) * 8;
  const size_t ga1 = (size_t)(bm + (c1 >> 2)) * K + (c1 & 3) * 8;
  const size_t gb0 = (size_t)(bn + (c0 >> 2)) * K + (c0 & 3) * 8;
  const size_t gb1 = (size_t)(bn + (c1 >> 2)) * K + (c1 & 3) * 8;

  if constexpr (AFP32) {
    for (int k0v = 0; k0v < K; k0v += 32) {
#pragma unroll
      for (int it = 0; it < 4; ++it) {
        const int c = it * 256 + tid;
        const int row = c >> 3, kc = c & 7;
        float4 v = *(const float4*)(Af + (size_t)(bm + row) * K + k0v + kc * 4);
        __hip_bfloat16 h[4] = {__float2bfloat16(v.x), __float2bfloat16(v.y),
                               __float2bfloat16(v.z), __float2bfloat16(v.w)};
        *(ushort4*)(Asm[0] + row * 32 + kc * 4) = *(ushort4*)h;
      }
      load_lds16(Bt + gb0 + k0v, Bsm[0] + wave * 1024);
      load_lds16(Bt + gb1 + k0v, Bsm[0] + wave * 1024 + 512);
      __syncthreads();
      bf16x8 af[4], bfr[4];
#pragma unroll
      for (int mt = 0; mt < 4; ++mt)
        af[mt] = *(const bf16x8*)(Asm[0] + (wm + mt * 16 + lr) * 32 + q * 8);
#pragma unroll
      for (int nt = 0; nt < 4; ++nt)
        bfr[nt] = *(const bf16x8*)(Bsm[0] + (wn + nt * 16 + lr) * 32 + q * 8);
#pragma unroll
      for (int mt = 0; mt < 4; ++mt)
#pragma unroll
        for (int nt = 0; nt < 4; ++nt)
          acc[mt][nt] = __builtin_amdgcn_mfma_f32_16x16x32_bf16(af[mt], bfr[nt], acc[mt][nt], 0, 0, 0);
      __syncthreads();
    }
  } else {
    auto stage = [&](int s, int kv) {
      load_lds16(A + ga0 + kv, Asm[s] + wave * 1024);
      load_lds16(A + ga1 + kv, Asm[s] + wave * 1024 + 512);
      load_lds16(Bt + gb0 + kv, Bsm[s] + wave * 1024);
      load_lds16(Bt + gb1 + kv, Bsm[s] + wave * 1024 + 512);
    };
    stage(0, 0);
    __syncthreads();
    int cur = 0;
    for (int kv = 0; kv < K; kv += 32) {
      if (kv + 32 < K) stage(cur ^ 1, kv + 32);
      bf16x8 af[4], bfr[4];
#pragma unroll
      for (int mt = 0; mt < 4; ++mt)
        af[mt] = *(const bf16x8*)(Asm[cur] + (wm + mt * 16 + lr) * 32 + q * 8);
#pragma unroll
      for (int nt = 0; nt < 4; ++nt)
        bfr[nt] = *(const bf16x8*)(Bsm[cur] + (wn + nt * 16 + lr) * 32 + q * 8);
#pragma unroll
      for (int mt = 0; mt < 4; ++mt)
#pragma unroll
        for (int nt = 0; nt < 4; ++nt)
          acc[mt][nt] = __builtin_amdgcn_mfma_f32_16x16x32_bf16(af[mt], bfr[nt], acc[mt][nt], 0, 0, 0);
      __syncthreads();
      cur ^= 1;
    }
  }

  // C/D layout: col = lane&15, row = (lane>>4)*4 + reg
#pragma unroll
  for (int mt = 0; mt < 4; ++mt) {
    const int rbase = bm + wm + mt * 16 + q * 4;
#pragma unroll
    for (int nt = 0; nt < 4; ++nt) {
      const int col = bn + wn + nt * 16 + lr;
#pragma unroll
      for (int r = 0; r < 4; ++r) {
        const int row = rbase + r;
        if (row < M)
          Cb[(size_t)row * 512 + col] = __float2bfloat16(fmaxf(acc[mt][nt][r], 0.f));
      }
    }
  }
  if (upd_raw) {
    float wt[4];
#pragma unroll
    for (int nt = 0; nt < 4; ++nt) wt[nt] = W_T[bn + wn + nt * 16 + lr];
#pragma unroll
    for (int mt = 0; mt < 4; ++mt) {
      const int rbase = bm + wm + mt * 16 + q * 4;
#pragma unroll
      for (int r = 0; r < 4; ++r) {
        float p = 0.f;
#pragma unroll
        for (int nt = 0; nt < 4; ++nt) {
          const float v = __bfloat162float(__float2bfloat16(fmaxf(acc[mt][nt][r], 0.f)));
          p += v * wt[nt];
        }
        p += __shfl_xor(p, 1); p += __shfl_xor(p, 2);
        p += __shfl_xor(p, 4); p += __shfl_xor(p, 8);
        if (lr == 0) atomicAdd((float*)&upd_raw[rbase + r], p);
      }
    }
  }
}

// ---------- cooperative tail: join levels 4..8 -> propagate -> tree_part ----------
// 512 blocks; per-level active blocks 512/256/128/64/32 (same wave-tile mapping
// as the verified join_level); grid.sync() between levels keeps occupancy while
// removing 6 launch boundaries.
__global__ __launch_bounds__(256, 2)
void tail_coop(__hip_bfloat16* __restrict__ levels, const __hip_bfloat16* __restrict__ Wt_j,
               const float* __restrict__ h0, const float* __restrict__ W_s,
               const float* __restrict__ inputs, float* __restrict__ attn_out,
               float* __restrict__ tp) {
  cg::grid_group grid = cg::this_grid();
  const int bid = blockIdx.x, tid = threadIdx.x;
  const int wave = tid >> 6, lane = tid & 63;
  const int q = lane >> 4, lr = lane & 15;
  __shared__ float part[256], ws[512], sc_sh[256], attn_sh[256], newattn[256];
  __shared__ float scs_sh;
  const int lvl_off[9] = {0, 0, 4194304, 6291456, 7340032,
                          7864320, 8126464, 8257536, 8323072};

  // levels 4..8
  for (int l = 4; l <= 8; ++l) {
    const int m_out = 256 >> l;
    if (bid < 32 * m_out) {
      const __hip_bfloat16* in = levels + lvl_off[l - 1];
      __hip_bfloat16* outp = levels + lvl_off[l];
      const int tile = bid * 4 + wave;
      const int mtile = tile >> 5, ntile = tile & 31;
      const __hip_bfloat16* ap = in + (size_t)(mtile * 16 + lr) * 1024 + q * 8;
      const __hip_bfloat16* bp = Wt_j + (size_t)(ntile * 16 + lr) * 1024 + q * 8;
      f32x4 acc = {0.f, 0.f, 0.f, 0.f};
#pragma unroll 8
      for (int k0 = 0; k0 < 1024; k0 += 32) {
        bf16x8 a  = *(const bf16x8*)(ap + k0);
        bf16x8 bb = *(const bf16x8*)(bp + k0);
        acc = __builtin_amdgcn_mfma_f32_16x16x32_bf16(a, bb, acc, 0, 0, 0);
      }
      const int col = ntile * 16 + lr;
      const int orow = mtile * 16 + q * 4;
#pragma unroll
      for (int r = 0; r < 4; ++r)
        outp[(size_t)(orow + r) * 512 + col] = __float2bfloat16(fmaxf(acc[r], 0.f));
    }
    __threadfence();
    grid.sync();
  }

  // propagate: node scores + top-down attention (blocks 0..63, b = bid)
  if (bid < 64) {
    const int b = bid;
    ws[tid] = W_s[tid]; ws[tid + 256] = W_s[tid + 256];
    float p = 0.f;
    for (int i = tid; i < 512; i += 256) p += h0[b * 512 + i] * W_s[512 + i];
    part[tid] = p; __syncthreads();
    for (int s = 128; s > 0; s >>= 1) { if (tid < s) part[tid] += part[tid + s]; __syncthreads(); }
    if (tid == 0) { scs_sh = part[0]; attn_sh[0] = 1.f; }
    __syncthreads();
    const float scs = scs_sh;
    const int rowbase[9] = {0, 0, 8192, 12288, 14336, 15360, 15872, 16128, 16256};
    const int nodeoff[9] = {0, 0, 128, 192, 224, 240, 248, 252, 254};
    for (int l = 1; l <= 8; ++l) {
      const int m = 256 >> l;
      for (int j0 = wave * 8; j0 < m; j0 += 32) {
        const int j = j0 + (lane >> 3), s = lane & 7;
        float qv = 0.f;
        if (j < m) {
          const __hip_bfloat16* xr = levels + (size_t)(rowbase[l] + b * m + j) * 512;
#pragma unroll
          for (int i = 0; i < 8; ++i) {
            const int k = (i * 8 + s) * 8;
            union { bf16x8 v; __hip_bfloat16 e[8]; } u;
            u.v = *(const bf16x8*)(xr + k);
#pragma unroll
            for (int jj = 0; jj < 8; ++jj) qv += __bfloat162float(u.e[jj]) * ws[k + jj];
          }
        }
        qv += __shfl_xor(qv, 1); qv += __shfl_xor(qv, 2); qv += __shfl_xor(qv, 4);
        if (s == 0 && j < m) sc_sh[nodeoff[l] + j] = qv;
      }
    }
    __syncthreads();
#pragma unroll
    for (int l = 8; l >= 1; --l) {
      const int m = 256 >> l;
      if (tid < m) {
        const float mr = sigmoidf_(sc_sh[nodeoff[l] + tid] + scs);
        const float a = attn_sh[tid];
        newattn[2 * tid]     = a * (1.f - mr);
        newattn[2 * tid + 1] = a * mr;
      }
      __syncthreads();
      if (tid < 2 * m) attn_sh[tid] = newattn[tid];
      __syncthreads();
    }
    attn_out[b * 256 + tid] = attn_sh[tid];
  }
  __threadfence();
  grid.sync();

  // tree_part (blocks 0..255: s = bid>>6, b = bid&63)
  if (bid < 256) {
    const int s = bid >> 6, b = bid & 63;
    if (tid < 64) part[tid] = attn_out[b * 256 + s * 64 + tid];
    __syncthreads();
    float acc0 = 0.f, acc1 = 0.f;
    const float* base = inputs + ((size_t)b * 256 + s * 64) * 512;
    for (int nn = 0; nn < 64; ++nn) {
      const float a = part[nn];
      const float* row = base + (size_t)nn * 512;
      acc0 += a * row[tid];
      acc1 += a * row[tid + 256];
    }
    tp[((size_t)s * 64 + b) * 512 + tid]       = acc0;
    tp[((size_t)s * 64 + b) * 512 + tid + 256] = acc1;
  }
}

// ---------- write-stage GEMM (512 tiles) + LSTM split-K (1024 units), one launch ----------
__global__ __launch_bounds__(256)
void write_lstm(const __hip_bfloat16* __restrict__ leaf, const __hip_bfloat16* __restrict__ Bt,
                const float* __restrict__ ctrl_h, const float* __restrict__ attn,
                const float* __restrict__ upd_raw, const float* __restrict__ ctrlT,
                float* __restrict__ Cf,
                const float* __restrict__ tp, const float* __restrict__ h0,
                const float* __restrict__ kern, const float* __restrict__ rec,
                float* __restrict__ Zp) {
  __shared__ __align__(16) __hip_bfloat16 Asm[2][128 * 32];
  __shared__ __align__(16) __hip_bfloat16 Bsm[2][128 * 32];
  const int bid = blockIdx.x, tid = threadIdx.x;

  if (bid < 512) {
    const int K = 512;
    const int wave = tid >> 6, lane = tid & 63;
    const int bm = (bid & 127) * 128, bn = (bid >> 7) * 128;
    const int wm = (wave >> 1) * 64, wn = (wave & 1) * 64;
    const int q = lane >> 4, lr = lane & 15;
    f32x4 acc[4][4] = {};
    const int c0 = wave * 128 + lane, c1 = c0 + 64;
    const size_t ga0 = (size_t)(bm + (c0 >> 2)) * K + (c0 & 3) * 8;
    const size_t ga1 = (size_t)(bm + (c1 >> 2)) * K + (c1 & 3) * 8;
    const size_t gb0 = (size_t)(bn + (c0 >> 2)) * K + (c0 & 3) * 8;
    const size_t gb1 = (size_t)(bn + (c1 >> 2)) * K + (c1 & 3) * 8;
    auto stage = [&](int s, int kv) {
      load_lds16(leaf + ga0 + kv, Asm[s] + wave * 1024);
      load_lds16(leaf + ga1 + kv, Asm[s] + wave * 1024 + 512);
      load_lds16(Bt + gb0 + kv, Bsm[s] + wave * 1024);
      load_lds16(Bt + gb1 + kv, Bsm[s] + wave * 1024 + 512);
    };
    stage(0, 0);
    __syncthreads();
    int cur = 0;
    for (int kv = 0; kv < K; kv += 32) {
      if (kv + 32 < K) stage(cur ^ 1, kv + 32);
      bf16x8 af[4], bfr[4];
#pragma unroll
      for (int mt = 0; mt < 4; ++mt)
        af[mt] = *(const bf16x8*)(Asm[cur] + (wm + mt * 16 + lr) * 32 + q * 8);
#pragma unroll
      for (int nt = 0; nt < 4; ++nt)
        bfr[nt] = *(const bf16x8*)(Bsm[cur] + (wn + nt * 16 + lr) * 32 + q * 8);
#pragma unroll
      for (int mt = 0; mt < 4; ++mt)
#pragma unroll
        for (int nt = 0; nt < 4; ++nt)
          acc[mt][nt] = __builtin_amdgcn_mfma_f32_16x16x32_bf16(af[mt], bfr[nt], acc[mt][nt], 0, 0, 0);
      __syncthreads();
      cur ^= 1;
    }
#pragma unroll
    for (int mt = 0; mt < 4; ++mt) {
      const int rbase = bm + wm + mt * 16 + q * 4;
#pragma unroll
      for (int r = 0; r < 4; ++r) {
        const int row = rbase + r;
        const float a = attn[row];
        const int bidx = row >> 8;
        const float u = sigmoidf_(upd_raw[row] + ctrlT[bidx]);
#pragma unroll
        for (int nt = 0; nt < 4; ++nt) {
          const int col = bn + wn + nt * 16 + lr;
          const float cand = sigmoidf_(acc[mt][nt][r] + ctrl_h[(size_t)bidx * 512 + col]);
          const float lf = __bfloat162float(leaf[(size_t)row * 512 + col]);
          const float w = u * cand + (1.f - u) * lf;
          Cf[(size_t)row * 512 + col] = a * w + (1.f - a) * lf;
        }
      }
    }
  } else {
    // LSTM split-K unit u = bid-512: x=u&7, y=(u>>3)&15, z=u>>7
    const int u = bid - 512;
    const int col = (u & 7) * 256 + tid;
    const int b0 = ((u >> 3) & 15) * 4;
    const int z = u >> 7;
    const float* W = (z < 4) ? (kern + (size_t)z * 128 * 2048)
                             : (rec + (size_t)(z - 4) * 128 * 2048);
    const int koff = (z & 3) * 128;
    float (*xs)[128] = (float(*)[128])(&Asm[0][0]);
    for (int i = tid; i < 512; i += 256) {
      int bb = i >> 7, k = i & 127;
      const size_t idx = (size_t)(b0 + bb) * 512 + koff + k;
      float x;
      if (z < 4) x = tp[idx] + tp[32768 + idx] + tp[65536 + idx] + tp[98304 + idx];
      else       x = h0[idx];
      xs[bb][k] = x;
    }
    __syncthreads();
    float a0 = 0.f, a1 = 0.f, a2 = 0.f, a3 = 0.f;
#pragma unroll 8
    for (int k = 0; k < 128; ++k) {
      const float w = W[(size_t)k * 2048 + col];
      a0 += xs[0][k] * w;
      a1 += xs[1][k] * w;
      a2 += xs[2][k] * w;
      a3 += xs[3][k] * w;
    }
    Zp[((size_t)z * 64 + b0 + 0) * 2048 + col] = a0;
    Zp[((size_t)z * 64 + b0 + 1) * 2048 + col] = a1;
    Zp[((size_t)z * 64 + b0 + 2) * 2048 + col] = a2;
    Zp[((size_t)z * 64 + b0 + 3) * 2048 + col] = a3;
  }
}

__global__ __launch_bounds__(256)
void lstm_combine(const float* __restrict__ Zp, const float* __restrict__ bias,
                  const float* __restrict__ c0,
                  float* __restrict__ out_h, float* __restrict__ out_c) {
  const int i = blockIdx.x * 256 + threadIdx.x;
  const int b = i >> 9, u = i & 511;
  float zi = bias[u], zf = bias[512 + u], zg = bias[1024 + u], zo = bias[1536 + u];
#pragma unroll
  for (int z = 0; z < 8; ++z) {
    const size_t base = ((size_t)z * 64 + b) * 2048;
    zi += Zp[base + u];
    zf += Zp[base + 512 + u];
    zg += Zp[base + 1024 + u];
    zo += Zp[base + 1536 + u];
  }
  const float c = sigmoidf_(zf) * c0[i] + sigmoidf_(zi) * tanhf(zg);
  out_h[i] = sigmoidf_(zo) * tanhf(c);
  out_c[i] = c;
}

extern "C" void kernel_launch(void* const* d_in, const int* in_sizes, int n_in,
                              void* d_out, int out_size, void* d_ws, size_t ws_size,
                              hipStream_t stream) {
  const float* inputs = (const float*)d_in[0];
  const float* h0     = (const float*)d_in[1];
  const float* c0     = (const float*)d_in[2];
  const float* W_t    = (const float*)d_in[3];
  const float* W_j    = (const float*)d_in[4];
  const float* W_s    = (const float*)d_in[5];
  const float* W_h    = (const float*)d_in[6];
  const float* W_T    = (const float*)d_in[7];
  const float* kern   = (const float*)d_in[8];
  const float* rec    = (const float*)d_in[9];
  const float* bias   = (const float*)d_in[10];
  float* out = (float*)d_out;

  char* p = (char*)d_ws;
  __hip_bfloat16* leaf_bf   = (__hip_bfloat16*)p; p += 16777216;   // 16384x512
  __hip_bfloat16* levels_bf = (__hip_bfloat16*)p; p += 16842752;   // 16320x512 + pad
  __hip_bfloat16* Wt_t      = (__hip_bfloat16*)p; p += 524288;
  __hip_bfloat16* Wt_j      = (__hip_bfloat16*)p; p += 1048576;
  __hip_bfloat16* Wt_h      = (__hip_bfloat16*)p; p += 524288;
  float* attn  = (float*)p; p += 65536;    // 64x256
  float* upd   = (float*)p; p += 65536;    // 64x256 (upd_raw partial dots)
  float* ch    = (float*)p; p += 131072;   // 64x512
  float* ctrlT = (float*)p; p += 4096;     // 64
  float* tp    = (float*)p; p += 524288;   // 4x64x512 tree partials
  float* Zp    = (float*)p; p += 4194304;  // 8x64x2048 LSTM split-K partials
  const bool use_cvt = ws_size >= (size_t)(p - (char*)d_ws) + 16777216;
  __hip_bfloat16* inputs_bf = (__hip_bfloat16*)p;  // valid only if use_cvt

  // 1. merged prep (cvt + transposes + ctrl + upd zero)
  if (use_cvt) {
    prep_all<true><<<4096 + 1024 + 192 + 16, 256, 0, stream>>>(
        inputs, W_t, W_j, W_h, W_T, h0, inputs_bf, Wt_t, Wt_j, Wt_h, ch, ctrlT, upd);
    // 2. leaf embed (DMA dbuf) + upd partials
    mfma_gemm<0, false><<<dim3(128, 4), 256, 0, stream>>>(
        inputs_bf, nullptr, Wt_t, 16384, 512,
        leaf_bf, nullptr, nullptr, nullptr, upd, nullptr, W_T, nullptr);
  } else {
    prep_all<false><<<1024 + 192 + 16, 256, 0, stream>>>(
        inputs, W_t, W_j, W_h, W_T, h0, nullptr, Wt_t, Wt_j, Wt_h, ch, ctrlT, upd);
    mfma_gemm<0, true><<<dim3(128, 4), 256, 0, stream>>>(
        nullptr, inputs, Wt_t, 16384, 512,
        leaf_bf, nullptr, nullptr, nullptr, upd, nullptr, W_T, nullptr);
  }

  // 3-5. join levels 1..3 as tiled MFMA GEMMs (dbuf)
  const int lvl_off_h[9] = {0, 0, 4194304, 6291456, 7340032,
                            7864320, 8126464, 8257536, 8323072};
  const __hip_bfloat16* Aptr = leaf_bf;
  for (int l = 1; l <= 3; ++l) {
    const int M = 64 * (256 >> l);
    __hip_bfloat16* Cl = levels_bf + lvl_off_h[l];
    mfma_gemm<0, false><<<dim3(M / 128, 4), 256, 0, stream>>>(
        Aptr, nullptr, Wt_j, M, 1024,
        Cl, nullptr, nullptr, nullptr, nullptr, nullptr, nullptr, nullptr);
    Aptr = Cl;
  }

  // 6. cooperative tail: levels 4..8 -> propagate -> tree_part
  {
    __hip_bfloat16* lv = levels_bf;
    const __hip_bfloat16* wj = Wt_j;
    const float* h0p = h0;
    const float* wsp = W_s;
    const float* inp = inputs;
    float* attnp = attn;
    float* tpp = tp;
    void* cargs[] = {&lv, &wj, &h0p, &wsp, &inp, &attnp, &tpp};
    hipLaunchCooperativeKernel((void*)tail_coop, dim3(512), dim3(256), cargs, 0, stream);
  }

  // 7. write-stage GEMM + LSTM split-K (independent, one launch)
  write_lstm<<<1536, 256, 0, stream>>>(leaf_bf, Wt_h, ch, attn, upd, ctrlT,
                                       out + 65536, tp, h0, kern, rec, Zp);

  // 8. LSTM combine
  lstm_combine<<<128, 256, 0, stream>>>(Zp, bias, c0, out, out + 32768);
}

// Round 7
// 345.585 us; speedup vs baseline: 2.6889x; 2.6889x over previous
//
#include <hip/hip_runtime.h>
#include <hip/hip_bf16.h>
#include <cstdint>
#include <cstddef>

// B=64, N=256 leaves, E=D=U=512.
// Outputs: h_new[64*512], c_new[64*512], leaf_h_new[64*256*512] concat flat fp32.

__device__ __forceinline__ float sigmoidf_(float x) { return 1.0f / (1.0f + __expf(-x)); }

typedef __attribute__((ext_vector_type(8))) short bf16x8;
typedef __attribute__((ext_vector_type(4))) float f32x4;

__device__ __forceinline__ void load_lds16(const void* g, void* l) {
  __builtin_amdgcn_global_load_lds((const __attribute__((address_space(1))) void*)g,
                                   (__attribute__((address_space(3))) void*)l, 16, 0, 0);
}

// ---------- merged prep: cvt_inputs + weight transposes + ctrl + upd zero ----------
// Flat block partition: [0,NC) cvt; [NC,NC+1024) transpose tiles;
// [NC+1024, NC+1216) ctrl units (128 ch + 64 ctrlT); last 16 zero upd.
// (verified in round 6)
template<bool DO_CVT>
__global__ __launch_bounds__(256)
void prep_all(const float* __restrict__ inputs, const float* __restrict__ W_t,
              const float* __restrict__ W_j, const float* __restrict__ W_h,
              const float* __restrict__ W_T, const float* __restrict__ h0,
              __hip_bfloat16* __restrict__ inputs_bf, __hip_bfloat16* __restrict__ Wt_t,
              __hip_bfloat16* __restrict__ Wt_j, __hip_bfloat16* __restrict__ Wt_h,
              float* __restrict__ ch, float* __restrict__ ctrlT, float* __restrict__ upd) {
  const int NC = DO_CVT ? 4096 : 0;
  const int bid = blockIdx.x, tid = threadIdx.x;
  __shared__ float shf[1056];
  if (DO_CVT && bid < NC) {
    const size_t i = ((size_t)bid * 256 + tid) * 8;
    float4 v0 = *(const float4*)(inputs + i);
    float4 v1 = *(const float4*)(inputs + i + 4);
    union { __hip_bfloat16 h[8]; bf16x8 v; } u;
    u.h[0] = __float2bfloat16(v0.x); u.h[1] = __float2bfloat16(v0.y);
    u.h[2] = __float2bfloat16(v0.z); u.h[3] = __float2bfloat16(v0.w);
    u.h[4] = __float2bfloat16(v1.x); u.h[5] = __float2bfloat16(v1.y);
    u.h[6] = __float2bfloat16(v1.z); u.h[7] = __float2bfloat16(v1.w);
    *(bf16x8*)(inputs_bf + i) = u.v;
  } else if (bid < NC + 1024) {
    const int t = bid - NC;
    int z, bx, by;
    if (t < 512)      { z = 1; bx = t & 31;         by = t >> 5; }
    else if (t < 768) { z = 0; bx = (t - 512) & 15; by = (t - 512) >> 4; }
    else              { z = 2; bx = (t - 768) & 15; by = (t - 768) >> 4; }
    const int K = (z == 1) ? 1024 : 512;
    const float* W = (z == 0) ? W_t : ((z == 1) ? W_j : W_h);
    __hip_bfloat16* Wt = (z == 0) ? Wt_t : ((z == 1) ? Wt_j : Wt_h);
    float (*sh)[33] = (float(*)[33])shf;
    const int tx = tid & 31, ty = tid >> 5;
    const int k0 = bx * 32, n0 = by * 32;
#pragma unroll
    for (int i = 0; i < 4; ++i)
      sh[ty + i * 8][tx] = W[(size_t)(k0 + ty + i * 8) * 512 + n0 + tx];
    __syncthreads();
#pragma unroll
    for (int i = 0; i < 4; ++i)
      Wt[(size_t)(n0 + ty + i * 8) * K + k0 + tx] = __float2bfloat16(sh[tx][ty + i * 8]);
  } else if (bid < NC + 1024 + 192) {
    const int u = bid - NC - 1024;
    if (u < 128) {
      const int b = u >> 1;
      float* hsh = shf;
      hsh[tid]       = h0[b * 512 + tid];
      hsh[tid + 256] = h0[b * 512 + 256 + tid];
      __syncthreads();
      const int col = (u & 1) * 256 + tid;
      const float* Wp = W_h + (size_t)512 * 512 + col;
      float s = 0.f;
#pragma unroll 8
      for (int k = 0; k < 512; ++k) s += hsh[k] * Wp[(size_t)k * 512];
      ch[(size_t)b * 512 + col] = s;
    } else {
      const int b = u - 128;
      float* part = shf;
      float p = 0.f;
      for (int i = tid; i < 512; i += 256) p += h0[b * 512 + i] * W_T[512 + i];
      part[tid] = p; __syncthreads();
      for (int s = 128; s > 0; s >>= 1) { if (tid < s) part[tid] += part[tid + s]; __syncthreads(); }
      if (tid == 0) ctrlT[b] = part[0];
    }
  } else {
    const int u = bid - NC - 1024 - 192;   // 0..15
    *(float4*)(upd + ((size_t)u * 256 + tid) * 4) = float4{0.f, 0.f, 0.f, 0.f};
  }
}

// ---------- bf16 MFMA GEMM: C = relu(A @ Bt^T), N=512 ----------
// Grid (M/128, 4). bf16 path: dbuf LDS + prefetch; AFP32: fused-cvt staging.
// If upd_raw != nullptr also accumulate per-row dot with W_T via shfl+atomicAdd.
template<int MODE, bool AFP32>
__global__ __launch_bounds__(256)
void mfma_gemm(const __hip_bfloat16* __restrict__ A, const float* __restrict__ Af,
               const __hip_bfloat16* __restrict__ Bt, int M, int K,
               __hip_bfloat16* __restrict__ Cb, float* __restrict__ Cf,
               const float* __restrict__ ctrl_h, const float* __restrict__ attn,
               const float* __restrict__ upd_raw, const __hip_bfloat16* __restrict__ leaf,
               const float* __restrict__ W_T, const float* __restrict__ ctrlT) {
  __shared__ __align__(16) __hip_bfloat16 Asm[2][128 * 32];
  __shared__ __align__(16) __hip_bfloat16 Bsm[2][128 * 32];
  const int tid = threadIdx.x;
  const int wave = tid >> 6, lane = tid & 63;
  const int bm = blockIdx.x * 128, bn = blockIdx.y * 128;
  const int wm = (wave >> 1) * 64, wn = (wave & 1) * 64;
  const int q = lane >> 4, lr = lane & 15;

  f32x4 acc[4][4] = {};

  const int c0 = wave * 128 + lane, c1 = c0 + 64;
  const size_t ga0 = (size_t)(bm + (c0 >> 2)) * K + (c0 & 3) * 8;
  const size_t ga1 = (size_t)(bm + (c1 >> 2)) * K + (c1 & 3) * 8;
  const size_t gb0 = (size_t)(bn + (c0 >> 2)) * K + (c0 & 3) * 8;
  const size_t gb1 = (size_t)(bn + (c1 >> 2)) * K + (c1 & 3) * 8;

  if constexpr (AFP32) {
    for (int k0v = 0; k0v < K; k0v += 32) {
#pragma unroll
      for (int it = 0; it < 4; ++it) {
        const int c = it * 256 + tid;
        const int row = c >> 3, kc = c & 7;
        float4 v = *(const float4*)(Af + (size_t)(bm + row) * K + k0v + kc * 4);
        __hip_bfloat16 h[4] = {__float2bfloat16(v.x), __float2bfloat16(v.y),
                               __float2bfloat16(v.z), __float2bfloat16(v.w)};
        *(ushort4*)(Asm[0] + row * 32 + kc * 4) = *(ushort4*)h;
      }
      load_lds16(Bt + gb0 + k0v, Bsm[0] + wave * 1024);
      load_lds16(Bt + gb1 + k0v, Bsm[0] + wave * 1024 + 512);
      __syncthreads();
      bf16x8 af[4], bfr[4];
#pragma unroll
      for (int mt = 0; mt < 4; ++mt)
        af[mt] = *(const bf16x8*)(Asm[0] + (wm + mt * 16 + lr) * 32 + q * 8);
#pragma unroll
      for (int nt = 0; nt < 4; ++nt)
        bfr[nt] = *(const bf16x8*)(Bsm[0] + (wn + nt * 16 + lr) * 32 + q * 8);
#pragma unroll
      for (int mt = 0; mt < 4; ++mt)
#pragma unroll
        for (int nt = 0; nt < 4; ++nt)
          acc[mt][nt] = __builtin_amdgcn_mfma_f32_16x16x32_bf16(af[mt], bfr[nt], acc[mt][nt], 0, 0, 0);
      __syncthreads();
    }
  } else {
    auto stage = [&](int s, int kv) {
      load_lds16(A + ga0 + kv, Asm[s] + wave * 1024);
      load_lds16(A + ga1 + kv, Asm[s] + wave * 1024 + 512);
      load_lds16(Bt + gb0 + kv, Bsm[s] + wave * 1024);
      load_lds16(Bt + gb1 + kv, Bsm[s] + wave * 1024 + 512);
    };
    stage(0, 0);
    __syncthreads();
    int cur = 0;
    for (int kv = 0; kv < K; kv += 32) {
      if (kv + 32 < K) stage(cur ^ 1, kv + 32);
      bf16x8 af[4], bfr[4];
#pragma unroll
      for (int mt = 0; mt < 4; ++mt)
        af[mt] = *(const bf16x8*)(Asm[cur] + (wm + mt * 16 + lr) * 32 + q * 8);
#pragma unroll
      for (int nt = 0; nt < 4; ++nt)
        bfr[nt] = *(const bf16x8*)(Bsm[cur] + (wn + nt * 16 + lr) * 32 + q * 8);
#pragma unroll
      for (int mt = 0; mt < 4; ++mt)
#pragma unroll
        for (int nt = 0; nt < 4; ++nt)
          acc[mt][nt] = __builtin_amdgcn_mfma_f32_16x16x32_bf16(af[mt], bfr[nt], acc[mt][nt], 0, 0, 0);
      __syncthreads();
      cur ^= 1;
    }
  }

  // C/D layout: col = lane&15, row = (lane>>4)*4 + reg
#pragma unroll
  for (int mt = 0; mt < 4; ++mt) {
    const int rbase = bm + wm + mt * 16 + q * 4;
#pragma unroll
    for (int nt = 0; nt < 4; ++nt) {
      const int col = bn + wn + nt * 16 + lr;
#pragma unroll
      for (int r = 0; r < 4; ++r) {
        const int row = rbase + r;
        if (row < M)
          Cb[(size_t)row * 512 + col] = __float2bfloat16(fmaxf(acc[mt][nt][r], 0.f));
      }
    }
  }
  if (upd_raw) {
    float wt[4];
#pragma unroll
    for (int nt = 0; nt < 4; ++nt) wt[nt] = W_T[bn + wn + nt * 16 + lr];
#pragma unroll
    for (int mt = 0; mt < 4; ++mt) {
      const int rbase = bm + wm + mt * 16 + q * 4;
#pragma unroll
      for (int r = 0; r < 4; ++r) {
        float p = 0.f;
#pragma unroll
        for (int nt = 0; nt < 4; ++nt) {
          const float v = __bfloat162float(__float2bfloat16(fmaxf(acc[mt][nt][r], 0.f)));
          p += v * wt[nt];
        }
        p += __shfl_xor(p, 1); p += __shfl_xor(p, 2);
        p += __shfl_xor(p, 4); p += __shfl_xor(p, 8);
        if (lr == 0) atomicAdd((float*)&upd_raw[rbase + r], p);
      }
    }
  }
}

// ---------- tail join level: one 16x16 tile per wave, no LDS (r5-verified) ----------
__global__ __launch_bounds__(256)
void join_level(const __hip_bfloat16* __restrict__ in, __hip_bfloat16* __restrict__ outp,
                const __hip_bfloat16* __restrict__ Wt_j) {
  const int wave = threadIdx.x >> 6, lane = threadIdx.x & 63;
  const int q = lane >> 4, lr = lane & 15;
  const int tile = blockIdx.x * 4 + wave;
  const int mtile = tile >> 5, ntile = tile & 31;
  const __hip_bfloat16* ap = in + (size_t)(mtile * 16 + lr) * 1024 + q * 8;
  const __hip_bfloat16* bp = Wt_j + (size_t)(ntile * 16 + lr) * 1024 + q * 8;
  f32x4 acc = {0.f, 0.f, 0.f, 0.f};
#pragma unroll 8
  for (int k0 = 0; k0 < 1024; k0 += 32) {
    bf16x8 a  = *(const bf16x8*)(ap + k0);
    bf16x8 bb = *(const bf16x8*)(bp + k0);
    acc = __builtin_amdgcn_mfma_f32_16x16x32_bf16(a, bb, acc, 0, 0, 0);
  }
  const int col = ntile * 16 + lr;
  const int orow = mtile * 16 + q * 4;
#pragma unroll
  for (int r = 0; r < 4; ++r)
    outp[(size_t)(orow + r) * 512 + col] = __float2bfloat16(fmaxf(acc[r], 0.f));
}

// ---------- node scores + top-down attention, fused per batch (r5-verified) ----------
__global__ __launch_bounds__(256)
void propagate_sc(const __hip_bfloat16* __restrict__ levels, const float* __restrict__ h0,
                  const float* __restrict__ W_s, float* __restrict__ attn_out) {
  const int b = blockIdx.x, tid = threadIdx.x;
  const int wave = tid >> 6, lane = tid & 63;
  __shared__ float part[256], ws[512], sc_sh[256], attn_sh[256], newattn[256];
  __shared__ float scs_sh;
  ws[tid] = W_s[tid]; ws[tid + 256] = W_s[tid + 256];
  float p = 0.f;
  for (int i = tid; i < 512; i += 256) p += h0[b * 512 + i] * W_s[512 + i];
  part[tid] = p; __syncthreads();
  for (int s = 128; s > 0; s >>= 1) { if (tid < s) part[tid] += part[tid + s]; __syncthreads(); }
  if (tid == 0) { scs_sh = part[0]; attn_sh[0] = 1.f; }
  __syncthreads();
  const float scs = scs_sh;
  const int rowbase[9] = {0, 0, 8192, 12288, 14336, 15360, 15872, 16128, 16256};
  const int nodeoff[9] = {0, 0, 128, 192, 224, 240, 248, 252, 254};
  for (int l = 1; l <= 8; ++l) {
    const int m = 256 >> l;
    for (int j0 = wave * 8; j0 < m; j0 += 32) {
      const int j = j0 + (lane >> 3), s = lane & 7;
      float q = 0.f;
      if (j < m) {
        const __hip_bfloat16* xr = levels + (size_t)(rowbase[l] + b * m + j) * 512;
#pragma unroll
        for (int i = 0; i < 8; ++i) {
          const int k = (i * 8 + s) * 8;
          union { bf16x8 v; __hip_bfloat16 e[8]; } u;
          u.v = *(const bf16x8*)(xr + k);
#pragma unroll
          for (int jj = 0; jj < 8; ++jj) q += __bfloat162float(u.e[jj]) * ws[k + jj];
        }
      }
      q += __shfl_xor(q, 1); q += __shfl_xor(q, 2); q += __shfl_xor(q, 4);
      if (s == 0 && j < m) sc_sh[nodeoff[l] + j] = q;
    }
  }
  __syncthreads();
#pragma unroll
  for (int l = 8; l >= 1; --l) {
    const int m = 256 >> l;
    if (tid < m) {
      const float mr = sigmoidf_(sc_sh[nodeoff[l] + tid] + scs);
      const float a = attn_sh[tid];
      newattn[2 * tid]     = a * (1.f - mr);
      newattn[2 * tid + 1] = a * mr;
    }
    __syncthreads();
    if (tid < 2 * m) attn_sh[tid] = newattn[tid];
    __syncthreads();
  }
  attn_out[b * 256 + tid] = attn_sh[tid];
}

// ---------- tree_out partials over (n-slice, batch) (r5-verified) ----------
__global__ __launch_bounds__(256)
void tree_part(const float* __restrict__ inputs, const float* __restrict__ attn,
               float* __restrict__ tp) {
  const int s = blockIdx.x, b = blockIdx.y;
  const int tid = threadIdx.x;
  __shared__ float a_sh[64];
  if (tid < 64) a_sh[tid] = attn[b * 256 + s * 64 + tid];
  __syncthreads();
  float acc0 = 0.f, acc1 = 0.f;
  const float* base = inputs + ((size_t)b * 256 + s * 64) * 512;
  for (int nn = 0; nn < 64; ++nn) {
    const float a = a_sh[nn];
    const float* row = base + (size_t)nn * 512;
    acc0 += a * row[tid];
    acc1 += a * row[tid + 256];
  }
  tp[((size_t)s * 64 + b) * 512 + tid]       = acc0;
  tp[((size_t)s * 64 + b) * 512 + tid + 256] = acc1;
}

// ---------- write-stage GEMM (512 tiles) + LSTM split-K (1024 units), one launch ----------
// (verified in round 6)
__global__ __launch_bounds__(256)
void write_lstm(const __hip_bfloat16* __restrict__ leaf, const __hip_bfloat16* __restrict__ Bt,
                const float* __restrict__ ctrl_h, const float* __restrict__ attn,
                const float* __restrict__ upd_raw, const float* __restrict__ ctrlT,
                float* __restrict__ Cf,
                const float* __restrict__ tp, const float* __restrict__ h0,
                const float* __restrict__ kern, const float* __restrict__ rec,
                float* __restrict__ Zp) {
  __shared__ __align__(16) __hip_bfloat16 Asm[2][128 * 32];
  __shared__ __align__(16) __hip_bfloat16 Bsm[2][128 * 32];
  const int bid = blockIdx.x, tid = threadIdx.x;

  if (bid < 512) {
    const int K = 512;
    const int wave = tid >> 6, lane = tid & 63;
    const int bm = (bid & 127) * 128, bn = (bid >> 7) * 128;
    const int wm = (wave >> 1) * 64, wn = (wave & 1) * 64;
    const int q = lane >> 4, lr = lane & 15;
    f32x4 acc[4][4] = {};
    const int c0 = wave * 128 + lane, c1 = c0 + 64;
    const size_t ga0 = (size_t)(bm + (c0 >> 2)) * K + (c0 & 3) * 8;
    const size_t ga1 = (size_t)(bm + (c1 >> 2)) * K + (c1 & 3) * 8;
    const size_t gb0 = (size_t)(bn + (c0 >> 2)) * K + (c0 & 3) * 8;
    const size_t gb1 = (size_t)(bn + (c1 >> 2)) * K + (c1 & 3) * 8;
    auto stage = [&](int s, int kv) {
      load_lds16(leaf + ga0 + kv, Asm[s] + wave * 1024);
      load_lds16(leaf + ga1 + kv, Asm[s] + wave * 1024 + 512);
      load_lds16(Bt + gb0 + kv, Bsm[s] + wave * 1024);
      load_lds16(Bt + gb1 + kv, Bsm[s] + wave * 1024 + 512);
    };
    stage(0, 0);
    __syncthreads();
    int cur = 0;
    for (int kv = 0; kv < K; kv += 32) {
      if (kv + 32 < K) stage(cur ^ 1, kv + 32);
      bf16x8 af[4], bfr[4];
#pragma unroll
      for (int mt = 0; mt < 4; ++mt)
        af[mt] = *(const bf16x8*)(Asm[cur] + (wm + mt * 16 + lr) * 32 + q * 8);
#pragma unroll
      for (int nt = 0; nt < 4; ++nt)
        bfr[nt] = *(const bf16x8*)(Bsm[cur] + (wn + nt * 16 + lr) * 32 + q * 8);
#pragma unroll
      for (int mt = 0; mt < 4; ++mt)
#pragma unroll
        for (int nt = 0; nt < 4; ++nt)
          acc[mt][nt] = __builtin_amdgcn_mfma_f32_16x16x32_bf16(af[mt], bfr[nt], acc[mt][nt], 0, 0, 0);
      __syncthreads();
      cur ^= 1;
    }
#pragma unroll
    for (int mt = 0; mt < 4; ++mt) {
      const int rbase = bm + wm + mt * 16 + q * 4;
#pragma unroll
      for (int r = 0; r < 4; ++r) {
        const int row = rbase + r;
        const float a = attn[row];
        const int bidx = row >> 8;
        const float u = sigmoidf_(upd_raw[row] + ctrlT[bidx]);
#pragma unroll
        for (int nt = 0; nt < 4; ++nt) {
          const int col = bn + wn + nt * 16 + lr;
          const float cand = sigmoidf_(acc[mt][nt][r] + ctrl_h[(size_t)bidx * 512 + col]);
          const float lf = __bfloat162float(leaf[(size_t)row * 512 + col]);
          const float w = u * cand + (1.f - u) * lf;
          Cf[(size_t)row * 512 + col] = a * w + (1.f - a) * lf;
        }
      }
    }
  } else {
    // LSTM split-K unit u = bid-512: x=u&7, y=(u>>3)&15, z=u>>7
    const int u = bid - 512;
    const int col = (u & 7) * 256 + tid;
    const int b0 = ((u >> 3) & 15) * 4;
    const int z = u >> 7;
    const float* W = (z < 4) ? (kern + (size_t)z * 128 * 2048)
                             : (rec + (size_t)(z - 4) * 128 * 2048);
    const int koff = (z & 3) * 128;
    float (*xs)[128] = (float(*)[128])(&Asm[0][0]);
    for (int i = tid; i < 512; i += 256) {
      int bb = i >> 7, k = i & 127;
      const size_t idx = (size_t)(b0 + bb) * 512 + koff + k;
      float x;
      if (z < 4) x = tp[idx] + tp[32768 + idx] + tp[65536 + idx] + tp[98304 + idx];
      else       x = h0[idx];
      xs[bb][k] = x;
    }
    __syncthreads();
    float a0 = 0.f, a1 = 0.f, a2 = 0.f, a3 = 0.f;
#pragma unroll 8
    for (int k = 0; k < 128; ++k) {
      const float w = W[(size_t)k * 2048 + col];
      a0 += xs[0][k] * w;
      a1 += xs[1][k] * w;
      a2 += xs[2][k] * w;
      a3 += xs[3][k] * w;
    }
    Zp[((size_t)z * 64 + b0 + 0) * 2048 + col] = a0;
    Zp[((size_t)z * 64 + b0 + 1) * 2048 + col] = a1;
    Zp[((size_t)z * 64 + b0 + 2) * 2048 + col] = a2;
    Zp[((size_t)z * 64 + b0 + 3) * 2048 + col] = a3;
  }
}

__global__ __launch_bounds__(256)
void lstm_combine(const float* __restrict__ Zp, const float* __restrict__ bias,
                  const float* __restrict__ c0,
                  float* __restrict__ out_h, float* __restrict__ out_c) {
  const int i = blockIdx.x * 256 + threadIdx.x;
  const int b = i >> 9, u = i & 511;
  float zi = bias[u], zf = bias[512 + u], zg = bias[1024 + u], zo = bias[1536 + u];
#pragma unroll
  for (int z = 0; z < 8; ++z) {
    const size_t base = ((size_t)z * 64 + b) * 2048;
    zi += Zp[base + u];
    zf += Zp[base + 512 + u];
    zg += Zp[base + 1024 + u];
    zo += Zp[base + 1536 + u];
  }
  const float c = sigmoidf_(zf) * c0[i] + sigmoidf_(zi) * tanhf(zg);
  out_h[i] = sigmoidf_(zo) * tanhf(c);
  out_c[i] = c;
}

extern "C" void kernel_launch(void* const* d_in, const int* in_sizes, int n_in,
                              void* d_out, int out_size, void* d_ws, size_t ws_size,
                              hipStream_t stream) {
  const float* inputs = (const float*)d_in[0];
  const float* h0     = (const float*)d_in[1];
  const float* c0     = (const float*)d_in[2];
  const float* W_t    = (const float*)d_in[3];
  const float* W_j    = (const float*)d_in[4];
  const float* W_s    = (const float*)d_in[5];
  const float* W_h    = (const float*)d_in[6];
  const float* W_T    = (const float*)d_in[7];
  const float* kern   = (const float*)d_in[8];
  const float* rec    = (const float*)d_in[9];
  const float* bias   = (const float*)d_in[10];
  float* out = (float*)d_out;

  char* p = (char*)d_ws;
  __hip_bfloat16* leaf_bf   = (__hip_bfloat16*)p; p += 16777216;   // 16384x512
  __hip_bfloat16* levels_bf = (__hip_bfloat16*)p; p += 16842752;   // 16320x512 + pad
  __hip_bfloat16* Wt_t      = (__hip_bfloat16*)p; p += 524288;
  __hip_bfloat16* Wt_j      = (__hip_bfloat16*)p; p += 1048576;
  __hip_bfloat16* Wt_h      = (__hip_bfloat16*)p; p += 524288;
  float* attn  = (float*)p; p += 65536;    // 64x256
  float* upd   = (float*)p; p += 65536;    // 64x256 (upd_raw partial dots)
  float* ch    = (float*)p; p += 131072;   // 64x512
  float* ctrlT = (float*)p; p += 4096;     // 64
  float* tp    = (float*)p; p += 524288;   // 4x64x512 tree partials
  float* Zp    = (float*)p; p += 4194304;  // 8x64x2048 LSTM split-K partials
  const bool use_cvt = ws_size >= (size_t)(p - (char*)d_ws) + 16777216;
  __hip_bfloat16* inputs_bf = (__hip_bfloat16*)p;  // valid only if use_cvt

  // 1. merged prep (cvt + transposes + ctrl + upd zero)
  if (use_cvt) {
    prep_all<true><<<4096 + 1024 + 192 + 16, 256, 0, stream>>>(
        inputs, W_t, W_j, W_h, W_T, h0, inputs_bf, Wt_t, Wt_j, Wt_h, ch, ctrlT, upd);
    // 2. leaf embed (DMA dbuf) + upd partials
    mfma_gemm<0, false><<<dim3(128, 4), 256, 0, stream>>>(
        inputs_bf, nullptr, Wt_t, 16384, 512,
        leaf_bf, nullptr, nullptr, nullptr, upd, nullptr, W_T, nullptr);
  } else {
    prep_all<false><<<1024 + 192 + 16, 256, 0, stream>>>(
        inputs, W_t, W_j, W_h, W_T, h0, nullptr, Wt_t, Wt_j, Wt_h, ch, ctrlT, upd);
    mfma_gemm<0, true><<<dim3(128, 4), 256, 0, stream>>>(
        nullptr, inputs, Wt_t, 16384, 512,
        leaf_bf, nullptr, nullptr, nullptr, upd, nullptr, W_T, nullptr);
  }

  // 3-5. join levels 1..3 as tiled MFMA GEMMs (dbuf)
  const int lvl_off_h[9] = {0, 0, 4194304, 6291456, 7340032,
                            7864320, 8126464, 8257536, 8323072};
  const __hip_bfloat16* Aptr = leaf_bf;
  for (int l = 1; l <= 3; ++l) {
    const int M = 64 * (256 >> l);
    __hip_bfloat16* Cl = levels_bf + lvl_off_h[l];
    mfma_gemm<0, false><<<dim3(M / 128, 4), 256, 0, stream>>>(
        Aptr, nullptr, Wt_j, M, 1024,
        Cl, nullptr, nullptr, nullptr, nullptr, nullptr, nullptr, nullptr);
    Aptr = Cl;
  }

  // 6-10. levels 4..8: LDS-free wave-tile MFMA, exact tiling (32*m_out blocks)
  for (int l = 4; l <= 8; ++l) {
    const int m_out = 256 >> l;
    join_level<<<32 * m_out, 256, 0, stream>>>(levels_bf + lvl_off_h[l - 1],
                                               levels_bf + lvl_off_h[l], Wt_j);
  }

  // 11. fused node-scores + top-down attn
  propagate_sc<<<64, 256, 0, stream>>>(levels_bf, h0, W_s, attn);

  // 12. tree_out partials (reduce folded into LSTM X-load)
  tree_part<<<dim3(4, 64), 256, 0, stream>>>(inputs, attn, tp);

  // 13. write-stage GEMM + LSTM split-K (independent, one launch)
  write_lstm<<<1536, 256, 0, stream>>>(leaf_bf, Wt_h, ch, attn, upd, ctrlT,
                                       out + 65536, tp, h0, kern, rec, Zp);

  // 14. LSTM combine
  lstm_combine<<<128, 256, 0, stream>>>(Zp, bias, c0, out, out + 32768);
}

// Round 8
// 331.047 us; speedup vs baseline: 2.8070x; 1.0439x over previous
//
#include <hip/hip_runtime.h>
#include <hip/hip_bf16.h>
#include <cstdint>
#include <cstddef>

// B=64, N=256 leaves, E=D=U=512.
// Outputs: h_new[64*512], c_new[64*512], leaf_h_new[64*256*512] concat flat fp32.

__device__ __forceinline__ float sigmoidf_(float x) { return 1.0f / (1.0f + __expf(-x)); }

typedef __attribute__((ext_vector_type(8))) short bf16x8;
typedef __attribute__((ext_vector_type(4))) float f32x4;

__device__ __forceinline__ void load_lds16(const void* g, void* l) {
  __builtin_amdgcn_global_load_lds((const __attribute__((address_space(1))) void*)g,
                                   (__attribute__((address_space(3))) void*)l, 16, 0, 0);
}

// ---------- bulk fp32 -> bf16 convert for inputs (8 elems/thread) ----------
__global__ __launch_bounds__(256)
void cvt_inputs(const float* __restrict__ in, __hip_bfloat16* __restrict__ outp) {
  const size_t i = ((size_t)blockIdx.x * 256 + threadIdx.x) * 8;
  float4 v0 = *(const float4*)(in + i);
  float4 v1 = *(const float4*)(in + i + 4);
  union { __hip_bfloat16 h[8]; bf16x8 v; } u;
  u.h[0] = __float2bfloat16(v0.x); u.h[1] = __float2bfloat16(v0.y);
  u.h[2] = __float2bfloat16(v0.z); u.h[3] = __float2bfloat16(v0.w);
  u.h[4] = __float2bfloat16(v1.x); u.h[5] = __float2bfloat16(v1.y);
  u.h[6] = __float2bfloat16(v1.z); u.h[7] = __float2bfloat16(v1.w);
  *(bf16x8*)(outp + i) = u.v;
}

// ---------- all three weight transposes in one launch ----------
__global__ __launch_bounds__(256)
void tconv_all(const float* __restrict__ W_t, const float* __restrict__ W_j,
               const float* __restrict__ W_h,
               __hip_bfloat16* __restrict__ Wt_t, __hip_bfloat16* __restrict__ Wt_j,
               __hip_bfloat16* __restrict__ Wt_h) {
  const int z = blockIdx.z;
  if (z != 1 && blockIdx.x >= 16) return;
  const int K = (z == 1) ? 1024 : 512;
  const float* W = (z == 0) ? W_t : ((z == 1) ? W_j : W_h);
  __hip_bfloat16* Wt = (z == 0) ? Wt_t : ((z == 1) ? Wt_j : Wt_h);
  __shared__ float sh[32][33];
  const int tx = threadIdx.x & 31, ty = threadIdx.x >> 5;
  const int k0 = blockIdx.x * 32, n0 = blockIdx.y * 32;
#pragma unroll
  for (int i = 0; i < 4; ++i)
    sh[ty + i * 8][tx] = W[(size_t)(k0 + ty + i * 8) * 512 + n0 + tx];
  __syncthreads();
#pragma unroll
  for (int i = 0; i < 4; ++i)
    Wt[(size_t)(n0 + ty + i * 8) * K + k0 + tx] = __float2bfloat16(sh[tx][ty + i * 8]);
}

// ---------- bf16 MFMA GEMM: C = epi(A[M,K] @ Bt^T), N=512 ----------
// Grid (M/128, 4): M-tile fastest-varying -> same-A blocks land on same XCD.
// bf16 path: double-buffered LDS, prefetch next K-tile before compute.
// MODE 0: relu -> bf16 Cb; if upd_raw != nullptr also accumulate per-row
//         partial dot with W_T via shfl-reduce + atomicAdd.
// MODE 1: write-stage epilogue -> fp32 Cf; u = sigmoid(upd_raw + ctrlT).
//         ch hoisted (block-uniform bidx); lf loads batched per mt-tile.
template<int MODE, bool AFP32>
__global__ __launch_bounds__(256)
void mfma_gemm(const __hip_bfloat16* __restrict__ A, const float* __restrict__ Af,
               const __hip_bfloat16* __restrict__ Bt, int M, int K,
               __hip_bfloat16* __restrict__ Cb, float* __restrict__ Cf,
               const float* __restrict__ ctrl_h, const float* __restrict__ attn,
               const float* __restrict__ upd_raw, const __hip_bfloat16* __restrict__ leaf,
               const float* __restrict__ W_T, const float* __restrict__ ctrlT) {
  __shared__ __align__(16) __hip_bfloat16 Asm[2][128 * 32];
  __shared__ __align__(16) __hip_bfloat16 Bsm[2][128 * 32];
  const int tid = threadIdx.x;
  const int wave = tid >> 6, lane = tid & 63;
  const int bm = blockIdx.x * 128, bn = blockIdx.y * 128;
  const int wm = (wave >> 1) * 64, wn = (wave & 1) * 64;
  const int q = lane >> 4, lr = lane & 15;

  f32x4 acc[4][4] = {};

  const int c0 = wave * 128 + lane, c1 = c0 + 64;
  const size_t ga0 = (size_t)(bm + (c0 >> 2)) * K + (c0 & 3) * 8;
  const size_t ga1 = (size_t)(bm + (c1 >> 2)) * K + (c1 & 3) * 8;
  const size_t gb0 = (size_t)(bn + (c0 >> 2)) * K + (c0 & 3) * 8;
  const size_t gb1 = (size_t)(bn + (c1 >> 2)) * K + (c1 & 3) * 8;

  if constexpr (AFP32) {
    for (int k0v = 0; k0v < K; k0v += 32) {
#pragma unroll
      for (int it = 0; it < 4; ++it) {
        const int c = it * 256 + tid;
        const int row = c >> 3, kc = c & 7;
        float4 v = *(const float4*)(Af + (size_t)(bm + row) * K + k0v + kc * 4);
        __hip_bfloat16 h[4] = {__float2bfloat16(v.x), __float2bfloat16(v.y),
                               __float2bfloat16(v.z), __float2bfloat16(v.w)};
        *(ushort4*)(Asm[0] + row * 32 + kc * 4) = *(ushort4*)h;
      }
      load_lds16(Bt + gb0 + k0v, Bsm[0] + wave * 1024);
      load_lds16(Bt + gb1 + k0v, Bsm[0] + wave * 1024 + 512);
      __syncthreads();
      bf16x8 af[4], bfr[4];
#pragma unroll
      for (int mt = 0; mt < 4; ++mt)
        af[mt] = *(const bf16x8*)(Asm[0] + (wm + mt * 16 + lr) * 32 + q * 8);
#pragma unroll
      for (int nt = 0; nt < 4; ++nt)
        bfr[nt] = *(const bf16x8*)(Bsm[0] + (wn + nt * 16 + lr) * 32 + q * 8);
#pragma unroll
      for (int mt = 0; mt < 4; ++mt)
#pragma unroll
        for (int nt = 0; nt < 4; ++nt)
          acc[mt][nt] = __builtin_amdgcn_mfma_f32_16x16x32_bf16(af[mt], bfr[nt], acc[mt][nt], 0, 0, 0);
      __syncthreads();
    }
  } else {
    auto stage = [&](int s, int kv) {
      load_lds16(A + ga0 + kv, Asm[s] + wave * 1024);
      load_lds16(A + ga1 + kv, Asm[s] + wave * 1024 + 512);
      load_lds16(Bt + gb0 + kv, Bsm[s] + wave * 1024);
      load_lds16(Bt + gb1 + kv, Bsm[s] + wave * 1024 + 512);
    };
    stage(0, 0);
    __syncthreads();
    int cur = 0;
    for (int kv = 0; kv < K; kv += 32) {
      if (kv + 32 < K) stage(cur ^ 1, kv + 32);
      bf16x8 af[4], bfr[4];
#pragma unroll
      for (int mt = 0; mt < 4; ++mt)
        af[mt] = *(const bf16x8*)(Asm[cur] + (wm + mt * 16 + lr) * 32 + q * 8);
#pragma unroll
      for (int nt = 0; nt < 4; ++nt)
        bfr[nt] = *(const bf16x8*)(Bsm[cur] + (wn + nt * 16 + lr) * 32 + q * 8);
#pragma unroll
      for (int mt = 0; mt < 4; ++mt)
#pragma unroll
        for (int nt = 0; nt < 4; ++nt)
          acc[mt][nt] = __builtin_amdgcn_mfma_f32_16x16x32_bf16(af[mt], bfr[nt], acc[mt][nt], 0, 0, 0);
      __syncthreads();
      cur ^= 1;
    }
  }

  // C/D layout: col = lane&15, row = (lane>>4)*4 + reg
  if (MODE == 0) {
#pragma unroll
    for (int mt = 0; mt < 4; ++mt) {
      const int rbase = bm + wm + mt * 16 + q * 4;
#pragma unroll
      for (int nt = 0; nt < 4; ++nt) {
        const int col = bn + wn + nt * 16 + lr;
#pragma unroll
        for (int r = 0; r < 4; ++r) {
          const int row = rbase + r;
          if (row < M)
            Cb[(size_t)row * 512 + col] = __float2bfloat16(fmaxf(acc[mt][nt][r], 0.f));
        }
      }
    }
    if (upd_raw) {
      float wt[4];
#pragma unroll
      for (int nt = 0; nt < 4; ++nt) wt[nt] = W_T[bn + wn + nt * 16 + lr];
#pragma unroll
      for (int mt = 0; mt < 4; ++mt) {
        const int rbase = bm + wm + mt * 16 + q * 4;
#pragma unroll
        for (int r = 0; r < 4; ++r) {
          float p = 0.f;
#pragma unroll
          for (int nt = 0; nt < 4; ++nt) {
            const float v = __bfloat162float(__float2bfloat16(fmaxf(acc[mt][nt][r], 0.f)));
            p += v * wt[nt];
          }
          p += __shfl_xor(p, 1); p += __shfl_xor(p, 2);
          p += __shfl_xor(p, 4); p += __shfl_xor(p, 8);
          if (lr == 0) atomicAdd((float*)&upd_raw[rbase + r], p);
        }
      }
    }
  } else {
    // bidx is block-uniform: a 128-row tile never straddles a 256-row batch.
    const int bidx = bm >> 8;
    const float ct = ctrlT[bidx];
    // hoist the 4 ch values (depend on nt only for a fixed lane)
    float chv[4];
#pragma unroll
    for (int nt = 0; nt < 4; ++nt)
      chv[nt] = ctrl_h[(size_t)bidx * 512 + bn + wn + nt * 16 + lr];
#pragma unroll
    for (int mt = 0; mt < 4; ++mt) {
      const int rbase = bm + wm + mt * 16 + q * 4;
      // batch the 16 lf loads + 4 a/u pairs for this mt ahead of the math
      float av[4], uv[4];
      ushort lfb[4][4];
#pragma unroll
      for (int r = 0; r < 4; ++r) {
        const int row = rbase + r;
        av[r] = attn[row];
        uv[r] = upd_raw[row];
#pragma unroll
        for (int nt = 0; nt < 4; ++nt)
          lfb[r][nt] = *(const ushort*)(leaf + (size_t)row * 512 + bn + wn + nt * 16 + lr);
      }
#pragma unroll
      for (int r = 0; r < 4; ++r) {
        const int row = rbase + r;
        const float a = av[r];
        const float u = sigmoidf_(uv[r] + ct);
#pragma unroll
        for (int nt = 0; nt < 4; ++nt) {
          const int col = bn + wn + nt * 16 + lr;
          const float cand = sigmoidf_(acc[mt][nt][r] + chv[nt]);
          __hip_bfloat16 lfh; *(ushort*)&lfh = lfb[r][nt];
          const float lf = __bfloat162float(lfh);
          const float w = u * cand + (1.f - u) * lf;
          Cf[(size_t)row * 512 + col] = a * w + (1.f - a) * lf;
        }
      }
    }
  }
}

// ---------- tail join level: one 16x16 tile per wave, no LDS (r5-verified) ----------
__global__ __launch_bounds__(256)
void join_level(const __hip_bfloat16* __restrict__ in, __hip_bfloat16* __restrict__ outp,
                const __hip_bfloat16* __restrict__ Wt_j) {
  const int wave = threadIdx.x >> 6, lane = threadIdx.x & 63;
  const int q = lane >> 4, lr = lane & 15;
  const int tile = blockIdx.x * 4 + wave;
  const int mtile = tile >> 5, ntile = tile & 31;
  const __hip_bfloat16* ap = in + (size_t)(mtile * 16 + lr) * 1024 + q * 8;
  const __hip_bfloat16* bp = Wt_j + (size_t)(ntile * 16 + lr) * 1024 + q * 8;
  f32x4 acc = {0.f, 0.f, 0.f, 0.f};
#pragma unroll 8
  for (int k0 = 0; k0 < 1024; k0 += 32) {
    bf16x8 a  = *(const bf16x8*)(ap + k0);
    bf16x8 bb = *(const bf16x8*)(bp + k0);
    acc = __builtin_amdgcn_mfma_f32_16x16x32_bf16(a, bb, acc, 0, 0, 0);
  }
  const int col = ntile * 16 + lr;
  const int orow = mtile * 16 + q * 4;
#pragma unroll
  for (int r = 0; r < 4; ++r)
    outp[(size_t)(orow + r) * 512 + col] = __float2bfloat16(fmaxf(acc[r], 0.f));
}

// ---------- merged ctrl prep: ch (x<2) + ctrlT (x==2), one launch ----------
__global__ __launch_bounds__(256)
void ctrl_prep(const float* __restrict__ h0, const float* __restrict__ W_h,
               const float* __restrict__ W_T, float* __restrict__ ch,
               float* __restrict__ ctrlT) {
  const int b = blockIdx.y, tid = threadIdx.x;
  if (blockIdx.x == 2) {
    __shared__ float part[256];
    float p = 0.f;
    for (int i = tid; i < 512; i += 256) p += h0[b * 512 + i] * W_T[512 + i];
    part[tid] = p; __syncthreads();
    for (int s = 128; s > 0; s >>= 1) { if (tid < s) part[tid] += part[tid + s]; __syncthreads(); }
    if (tid == 0) ctrlT[b] = part[0];
  } else {
    __shared__ float hsh[512];
    hsh[tid]       = h0[b * 512 + tid];
    hsh[tid + 256] = h0[b * 512 + 256 + tid];
    __syncthreads();
    const int col = blockIdx.x * 256 + tid;
    const float* Wp = W_h + (size_t)512 * 512 + col;
    float s = 0.f;
#pragma unroll 8
    for (int k = 0; k < 512; ++k) s += hsh[k] * Wp[(size_t)k * 512];
    ch[(size_t)b * 512 + col] = s;
  }
}

// ---------- node scores + top-down attention, fused per batch (r5-verified) ----------
__global__ __launch_bounds__(256)
void propagate_sc(const __hip_bfloat16* __restrict__ levels, const float* __restrict__ h0,
                  const float* __restrict__ W_s, float* __restrict__ attn_out) {
  const int b = blockIdx.x, tid = threadIdx.x;
  const int wave = tid >> 6, lane = tid & 63;
  __shared__ float part[256], ws[512], sc_sh[256], attn_sh[256], newattn[256];
  __shared__ float scs_sh;
  ws[tid] = W_s[tid]; ws[tid + 256] = W_s[tid + 256];
  float p = 0.f;
  for (int i = tid; i < 512; i += 256) p += h0[b * 512 + i] * W_s[512 + i];
  part[tid] = p; __syncthreads();
  for (int s = 128; s > 0; s >>= 1) { if (tid < s) part[tid] += part[tid + s]; __syncthreads(); }
  if (tid == 0) { scs_sh = part[0]; attn_sh[0] = 1.f; }
  __syncthreads();
  const float scs = scs_sh;
  const int rowbase[9] = {0, 0, 8192, 12288, 14336, 15360, 15872, 16128, 16256};
  const int nodeoff[9] = {0, 0, 128, 192, 224, 240, 248, 252, 254};
  for (int l = 1; l <= 8; ++l) {
    const int m = 256 >> l;
    for (int j0 = wave * 8; j0 < m; j0 += 32) {
      const int j = j0 + (lane >> 3), s = lane & 7;
      float q = 0.f;
      if (j < m) {
        const __hip_bfloat16* xr = levels + (size_t)(rowbase[l] + b * m + j) * 512;
#pragma unroll
        for (int i = 0; i < 8; ++i) {
          const int k = (i * 8 + s) * 8;
          union { bf16x8 v; __hip_bfloat16 e[8]; } u;
          u.v = *(const bf16x8*)(xr + k);
#pragma unroll
          for (int jj = 0; jj < 8; ++jj) q += __bfloat162float(u.e[jj]) * ws[k + jj];
        }
      }
      q += __shfl_xor(q, 1); q += __shfl_xor(q, 2); q += __shfl_xor(q, 4);
      if (s == 0 && j < m) sc_sh[nodeoff[l] + j] = q;
    }
  }
  __syncthreads();
#pragma unroll
  for (int l = 8; l >= 1; --l) {
    const int m = 256 >> l;
    if (tid < m) {
      const float mr = sigmoidf_(sc_sh[nodeoff[l] + tid] + scs);
      const float a = attn_sh[tid];
      newattn[2 * tid]     = a * (1.f - mr);
      newattn[2 * tid + 1] = a * mr;
    }
    __syncthreads();
    if (tid < 2 * m) attn_sh[tid] = newattn[tid];
    __syncthreads();
  }
  attn_out[b * 256 + tid] = attn_sh[tid];
}

// ---------- tree_out partials over (n-slice, batch) (r5-verified) ----------
__global__ __launch_bounds__(256)
void tree_part(const float* __restrict__ inputs, const float* __restrict__ attn,
               float* __restrict__ tp) {
  const int s = blockIdx.x, b = blockIdx.y;
  const int tid = threadIdx.x;
  __shared__ float a_sh[64];
  if (tid < 64) a_sh[tid] = attn[b * 256 + s * 64 + tid];
  __syncthreads();
  float acc0 = 0.f, acc1 = 0.f;
  const float* base = inputs + ((size_t)b * 256 + s * 64) * 512;
  for (int nn = 0; nn < 64; ++nn) {
    const float a = a_sh[nn];
    const float* row = base + (size_t)nn * 512;
    acc0 += a * row[tid];
    acc1 += a * row[tid + 256];
  }
  tp[((size_t)s * 64 + b) * 512 + tid]       = acc0;
  tp[((size_t)s * 64 + b) * 512 + tid + 256] = acc1;
}

// ---------- LSTM split-K (tree_reduce folded into the X-load) ----------
__global__ __launch_bounds__(256)
void lstm_gemm_splitk(const float* __restrict__ tp, const float* __restrict__ h0,
                      const float* __restrict__ kern, const float* __restrict__ rec,
                      float* __restrict__ Zp) {
  const int tid = threadIdx.x;
  const int col = blockIdx.x * 256 + tid;
  const int b0 = blockIdx.y * 4;
  const int z = blockIdx.z;
  const float* W = (z < 4) ? (kern + (size_t)z * 128 * 2048)
                           : (rec + (size_t)(z - 4) * 128 * 2048);
  const int koff = (z & 3) * 128;
  __shared__ float xs[4][128];
  for (int i = tid; i < 512; i += 256) {
    int bb = i >> 7, k = i & 127;
    const size_t idx = (size_t)(b0 + bb) * 512 + koff + k;
    float x;
    if (z < 4) x = tp[idx] + tp[32768 + idx] + tp[65536 + idx] + tp[98304 + idx];
    else       x = h0[idx];
    xs[bb][k] = x;
  }
  __syncthreads();
  float a0 = 0.f, a1 = 0.f, a2 = 0.f, a3 = 0.f;
#pragma unroll 8
  for (int k = 0; k < 128; ++k) {
    const float w = W[(size_t)k * 2048 + col];
    a0 += xs[0][k] * w;
    a1 += xs[1][k] * w;
    a2 += xs[2][k] * w;
    a3 += xs[3][k] * w;
  }
  Zp[((size_t)z * 64 + b0 + 0) * 2048 + col] = a0;
  Zp[((size_t)z * 64 + b0 + 1) * 2048 + col] = a1;
  Zp[((size_t)z * 64 + b0 + 2) * 2048 + col] = a2;
  Zp[((size_t)z * 64 + b0 + 3) * 2048 + col] = a3;
}

__global__ __launch_bounds__(256)
void lstm_combine(const float* __restrict__ Zp, const float* __restrict__ bias,
                  const float* __restrict__ c0,
                  float* __restrict__ out_h, float* __restrict__ out_c) {
  const int i = blockIdx.x * 256 + threadIdx.x;
  const int b = i >> 9, u = i & 511;
  float zi = bias[u], zf = bias[512 + u], zg = bias[1024 + u], zo = bias[1536 + u];
#pragma unroll
  for (int z = 0; z < 8; ++z) {
    const size_t base = ((size_t)z * 64 + b) * 2048;
    zi += Zp[base + u];
    zf += Zp[base + 512 + u];
    zg += Zp[base + 1024 + u];
    zo += Zp[base + 1536 + u];
  }
  const float c = sigmoidf_(zf) * c0[i] + sigmoidf_(zi) * tanhf(zg);
  out_h[i] = sigmoidf_(zo) * tanhf(c);
  out_c[i] = c;
}

extern "C" void kernel_launch(void* const* d_in, const int* in_sizes, int n_in,
                              void* d_out, int out_size, void* d_ws, size_t ws_size,
                              hipStream_t stream) {
  const float* inputs = (const float*)d_in[0];
  const float* h0     = (const float*)d_in[1];
  const float* c0     = (const float*)d_in[2];
  const float* W_t    = (const float*)d_in[3];
  const float* W_j    = (const float*)d_in[4];
  const float* W_s    = (const float*)d_in[5];
  const float* W_h    = (const float*)d_in[6];
  const float* W_T    = (const float*)d_in[7];
  const float* kern   = (const float*)d_in[8];
  const float* rec    = (const float*)d_in[9];
  const float* bias   = (const float*)d_in[10];
  float* out = (float*)d_out;

  char* p = (char*)d_ws;
  __hip_bfloat16* leaf_bf   = (__hip_bfloat16*)p; p += 16777216;   // 16384x512
  __hip_bfloat16* levels_bf = (__hip_bfloat16*)p; p += 16842752;   // 16320x512 + pad
  __hip_bfloat16* Wt_t      = (__hip_bfloat16*)p; p += 524288;
  __hip_bfloat16* Wt_j      = (__hip_bfloat16*)p; p += 1048576;
  __hip_bfloat16* Wt_h      = (__hip_bfloat16*)p; p += 524288;
  float* attn  = (float*)p; p += 65536;    // 64x256
  float* upd   = (float*)p; p += 65536;    // 64x256 (upd_raw partial dots)
  float* ch    = (float*)p; p += 131072;   // 64x512
  float* ctrlT = (float*)p; p += 4096;     // 64
  float* tp    = (float*)p; p += 524288;   // 4x64x512 tree partials
  float* Zp    = (float*)p; p += 4194304;  // 8x64x2048 LSTM split-K partials
  const bool use_cvt = ws_size >= (size_t)(p - (char*)d_ws) + 16777216;
  __hip_bfloat16* inputs_bf = (__hip_bfloat16*)p;  // valid only if use_cvt

  // prep (independent)
  tconv_all<<<dim3(32, 16, 3), 256, 0, stream>>>(W_t, W_j, W_h, Wt_t, Wt_j, Wt_h);
  ctrl_prep<<<dim3(3, 64), 256, 0, stream>>>(h0, W_h, W_T, ch, ctrlT);
  hipMemsetAsync(upd, 0, 16384 * sizeof(float), stream);

  // leaf embed (computes upd_raw partials in epilogue)
  if (use_cvt) {
    cvt_inputs<<<4096, 256, 0, stream>>>(inputs, inputs_bf);
    mfma_gemm<0, false><<<dim3(128, 4), 256, 0, stream>>>(
        inputs_bf, nullptr, Wt_t, 16384, 512,
        leaf_bf, nullptr, nullptr, nullptr, upd, nullptr, W_T, nullptr);
  } else {
    mfma_gemm<0, true><<<dim3(128, 4), 256, 0, stream>>>(
        nullptr, inputs, Wt_t, 16384, 512,
        leaf_bf, nullptr, nullptr, nullptr, upd, nullptr, W_T, nullptr);
  }

  // join levels 1..3 as tiled MFMA GEMMs (dbuf)
  const int lvl_off_h[9] = {0, 0, 4194304, 6291456, 7340032,
                            7864320, 8126464, 8257536, 8323072};
  const __hip_bfloat16* Aptr = leaf_bf;
  for (int l = 1; l <= 3; ++l) {
    const int M = 64 * (256 >> l);
    __hip_bfloat16* Cl = levels_bf + lvl_off_h[l];
    mfma_gemm<0, false><<<dim3(M / 128, 4), 256, 0, stream>>>(
        Aptr, nullptr, Wt_j, M, 1024,
        Cl, nullptr, nullptr, nullptr, nullptr, nullptr, nullptr, nullptr);
    Aptr = Cl;
  }
  // levels 4..8: LDS-free wave-tile MFMA, exact tiling (32*m_out blocks)
  for (int l = 4; l <= 8; ++l) {
    const int m_out = 256 >> l;
    join_level<<<32 * m_out, 256, 0, stream>>>(levels_bf + lvl_off_h[l - 1],
                                               levels_bf + lvl_off_h[l], Wt_j);
  }

  // fused node-scores + top-down attn
  propagate_sc<<<64, 256, 0, stream>>>(levels_bf, h0, W_s, attn);

  // tree_out partials (reduce folded into LSTM X-load)
  tree_part<<<dim3(4, 64), 256, 0, stream>>>(inputs, attn, tp);

  // write stage -> leaf_h_new (fp32) at out[65536:]; u from upd_raw+ctrlT
  mfma_gemm<1, false><<<dim3(128, 4), 256, 0, stream>>>(
      leaf_bf, nullptr, Wt_h, 16384, 512,
      nullptr, out + 65536, ch, attn, upd, leaf_bf, nullptr, ctrlT);

  // LSTM (r2-verified split-K)
  lstm_gemm_splitk<<<dim3(8, 16, 8), 256, 0, stream>>>(tp, h0, kern, rec, Zp);
  lstm_combine<<<128, 256, 0, stream>>>(Zp, bias, c0, out, out + 32768);
}